// Round 3
// baseline (190.520 us; speedup 1.0000x reference)
//
#include <hip/hip_runtime.h>

#define NT 64
#define NB 8192
#define NS 32
#define NF 16
#define DT 0.05f
#define FP_ITERS 3

typedef float f32x2 __attribute__((ext_vector_type(2)));
typedef float f32x4 __attribute__((ext_vector_type(4)));

// tanh(x) = 1 - 2/(1 + exp2(K x)), K = 2*log2(e). 6 VALU ops per pair.
__device__ __forceinline__ f32x2 tanh2(f32x2 x) {
    const float K = 2.8853900817779268f;
    float e0 = __builtin_amdgcn_exp2f(K * x[0]);
    float e1 = __builtin_amdgcn_exp2f(K * x[1]);
    float r0 = __builtin_amdgcn_rcpf(e0 + 1.0f);
    float r1 = __builtin_amdgcn_rcpf(e1 + 1.0f);
    f32x2 r;
    r[0] = fmaf(-2.0f, r0, 1.0f);
    r[1] = fmaf(-2.0f, r1, 1.0f);
    return r;
}

// Rotate by 1 within each 16-lane row via DPP (row_ror:1 = ctrl 0x121).
// Pure VALU op — zero DS-pipe usage (R2 lesson: kernel was DS-pipe-bound at
// 74-83% with LDS broadcast; DPP moves the exchange to the VALU pipe).
__device__ __forceinline__ float ror1f(float v) {
    return __int_as_float(__builtin_amdgcn_update_dpp(
        0, __float_as_int(v), 0x121, 0xF, 0xF, true));
}

// Lane map: lane = b*16 + p; b in [0,4) = batch within wave, p in [0,16) =
// state pair (this lane owns y[2p],y[2p+1] of its batch and computes those two
// outputs). 4 batches/wave -> 2048 waves = 2/SIMD. The y all-to-all needed by
// the dot product is done by rotating each lane's OWN pair around the 16-lane
// row with DPP while the W registers are preloaded in rotation order — the
// inner loop touches no memory at all (no LDS, no barriers, no clobbers).
__global__ __launch_bounds__(256, 2) void rnes_kernel(
    const float* __restrict__ y0,
    const float* __restrict__ forces,
    const float* __restrict__ W,
    const float* __restrict__ U,
    const float* __restrict__ bias,
    float* __restrict__ out)
{
    const int lane = threadIdx.x & 63;
    const int wv   = threadIdx.x >> 6;
    const int b    = lane >> 4;
    const int p    = lane & 15;
    const int batch = blockIdx.x * 16 + wv * 4 + b;

    // One-time DPP direction probe (immune to row_ror receive-direction
    // ambiguity): after one rotation this lane holds the lane-id it received
    // from; select W rotation order to match. dir = +1 or 15 (== -1 mod 16).
    const int got = __builtin_amdgcn_update_dpp(0, p, 0x121, 0xF, 0xF, true) & 15;
    const int dir = (got == ((p + 1) & 15)) ? 1 : 15;

    // Rotated W pair-columns: at rotation step j this lane holds the y-pair of
    // index q = (p + dir*j) & 15. Wa[j] multiplies y[2q], Wb[j] multiplies
    // y[2q+1]; component 0 -> output row 2p, component 1 -> row 2p+1.
    // 64 VGPRs. Scalar init loads (once, L1-broadcast across b-groups).
    f32x2 Wa[16], Wb[16];
#pragma unroll
    for (int j = 0; j < 16; ++j) {
        const int q = (p + dir * j) & 15;
        Wa[j] = (f32x2){ W[(2*p) * NS + 2*q],     W[(2*p+1) * NS + 2*q]     };
        Wb[j] = (f32x2){ W[(2*p) * NS + 2*q + 1], W[(2*p+1) * NS + 2*q + 1] };
    }

    // U2[f] = (U[2p][f], U[2p+1][f]) — 32 VGPRs
    f32x2 U2[NF];
#pragma unroll
    for (int f = 0; f < NF; f += 4) {
        f32x4 r0 = *(const f32x4*)(U + (2*p)   * NF + f);
        f32x4 r1 = *(const f32x4*)(U + (2*p+1) * NF + f);
#pragma unroll
        for (int e = 0; e < 4; ++e) U2[f+e] = (f32x2){r0[e], r1[e]};
    }
    const f32x2 b2 = *(const f32x2*)(bias + 2*p);

    // y_prev, out[0] = y0
    f32x2 yp = *(const f32x2*)(y0 + (size_t)batch * NS + 2*p);
    __builtin_nontemporal_store(yp, (f32x2*)(out + (size_t)batch * NS + 2*p));

    // register prefetch of forces[1]: broadcast f32x4 x4 per b-group.
    // nontemporal: each force line is read exactly once.
    const size_t fstep = (size_t)NB * NF;
    const f32x4* fb = (const f32x4*)(forces + (size_t)batch * NF);
    f32x4 upf[4];
#pragma unroll
    for (int j = 0; j < 4; ++j)
        upf[j] = __builtin_nontemporal_load(&fb[(fstep >> 2) + j]);

    for (int k = 1; k < NT; ++k) {
        // fu = U u + b from prefetched registers (2 accumulators)
        f32x2 a0 = b2, a1 = (f32x2){0.f, 0.f};
#pragma unroll
        for (int f = 0; f < NF; f += 4) {
            f32x4 u4 = upf[f >> 2];
            a0 = U2[f+0] * u4[0] + a0;
            a1 = U2[f+1] * u4[1] + a1;
            a0 = U2[f+2] * u4[2] + a0;
            a1 = U2[f+3] * u4[3] + a1;
        }
        const f32x2 fu = a0 + a1;

        // prefetch next step's forces (in flight across all 3 iterations)
        {
            int kn = (k + 1 < NT) ? (k + 1) : (NT - 1);
#pragma unroll
            for (int j = 0; j < 4; ++j)
                upf[j] = __builtin_nontemporal_load(&fb[(size_t)kn * (fstep >> 2) + j]);
        }

        // fixed-point iterations, warm start y_prev. Pure-register: the
        // 16-step DPP ring rotation walks every y-pair past every lane.
        f32x2 y = yp;
#pragma unroll
        for (int it = 0; it < FP_ITERS; ++it) {
            f32x2 z0 = fu, z1 = (f32x2){0.f, 0.f};
            float yc0 = y[0], yc1 = y[1];
#pragma unroll
            for (int j = 0; j < 16; ++j) {
                z0 = Wa[j] * yc0 + z0;
                z1 = Wb[j] * yc1 + z1;
                if (j < 15) { yc0 = ror1f(yc0); yc1 = ror1f(yc1); }
            }
            f32x2 t = tanh2(z0 + z1);
            y[0] = fmaf(DT, t[0], yp[0]);
            y[1] = fmaf(DT, t[1], yp[1]);
        }

        yp = y;
        __builtin_nontemporal_store(y, (f32x2*)(out + ((size_t)k * NB + batch) * NS + 2*p));
    }
}

extern "C" void kernel_launch(void* const* d_in, const int* in_sizes, int n_in,
                              void* d_out, int out_size, void* d_ws, size_t ws_size,
                              hipStream_t stream) {
    const float* y0     = (const float*)d_in[0];
    const float* forces = (const float*)d_in[1];
    const float* W      = (const float*)d_in[2];
    const float* U      = (const float*)d_in[3];
    const float* b      = (const float*)d_in[4];
    float* out = (float*)d_out;

    dim3 grid(NB / 16);   // 512 blocks x 4 waves x 4 batches = 8192
    dim3 block(256);
    rnes_kernel<<<grid, block, 0, stream>>>(y0, forces, W, U, b, out);
}

// Round 5
// 171.209 us; speedup vs baseline: 1.1128x; 1.1128x over previous
//
#include <hip/hip_runtime.h>

#define NT 64
#define NB 8192
#define NS 32
#define NF 16
#define DT 0.05f
#define FP_ITERS 3

typedef float f32x2 __attribute__((ext_vector_type(2)));
typedef float f32x4 __attribute__((ext_vector_type(4)));

// tanh(x) = 1 - 2/(1 + exp2(K x)), K = 2*log2(e). 6 VALU ops per pair.
__device__ __forceinline__ f32x2 tanh2(f32x2 x) {
    const float K = 2.8853900817779268f;
    float e0 = __builtin_amdgcn_exp2f(K * x[0]);
    float e1 = __builtin_amdgcn_exp2f(K * x[1]);
    float r0 = __builtin_amdgcn_rcpf(e0 + 1.0f);
    float r1 = __builtin_amdgcn_rcpf(e1 + 1.0f);
    f32x2 r;
    r[0] = fmaf(-2.0f, r0, 1.0f);
    r[1] = fmaf(-2.0f, r1, 1.0f);
    return r;
}

// Lane map: lane = b*16 + p; b in [0,4) = batch within wave (row_ror rotates
// within 16-lane rows -> exchange is batch-contained), p in [0,16) = state
// pair. 4 batches/wave -> 2048 waves = 2/SIMD.
//
// R3 post-mortem: VGPR_Count 72 vs ~130 live floats -> LLVM rematerialized the
// W gather loads INSIDE the loop (up to 64 scalar global loads/iter), and the
// serial ror:1 ring chained 15 dependent cross-lane hops. Fixes here:
//  (a) independent hops: row_ror:j (j=1..15) all source the ORIGINAL y regs
//      (DPP ctrl must be a LITERAL -> expanded via macro, R4 compile lesson);
//  (b) W values pinned via asm "+v" pass-through — an asm def cannot be
//      rematerialized, forcing true register residency (cap is 256 VGPRs at
//      __launch_bounds__(256,2), so no spill pressure);
//  (c) inner loop touches NO memory: no LDS, no barriers, no global.
__global__ __launch_bounds__(256, 2) void rnes_kernel(
    const float* __restrict__ y0,
    const float* __restrict__ forces,
    const float* __restrict__ W,
    const float* __restrict__ U,
    const float* __restrict__ bias,
    float* __restrict__ out)
{
    const int lane = threadIdx.x & 63;
    const int wv   = threadIdx.x >> 6;
    const int b    = lane >> 4;
    const int p    = lane & 15;
    const int batch = blockIdx.x * 16 + wv * 4 + b;

    // One-time DPP direction probe (immune to row_ror receive-direction
    // ambiguity): after ror:1 this lane holds the p of the lane it received
    // from; rotations compose, so ror:j delivers lane (p + dir*j) & 15.
    const int got = __builtin_amdgcn_update_dpp(0, p, 0x121, 0xF, 0xF, true) & 15;
    const int dir = (got == ((p + 1) & 15)) ? 1 : 15;

    // W gathered in rotation order: at hop j this lane receives the y-pair of
    // q = (p + dir*j) & 15. Wr<r><c>[j] = W[2p+r][2q+c]. 64 scalar VGPRs.
    float Wr00[16], Wr01[16], Wr10[16], Wr11[16];
#pragma unroll
    for (int j = 0; j < 16; ++j) {
        const int q = (p + dir * j) & 15;
        Wr00[j] = W[(2*p)   * NS + 2*q];
        Wr01[j] = W[(2*p)   * NS + 2*q + 1];
        Wr10[j] = W[(2*p+1) * NS + 2*q];
        Wr11[j] = W[(2*p+1) * NS + 2*q + 1];
    }
    // Pin: defs become asm ops -> not rematerializable -> stay resident.
#pragma unroll
    for (int j = 0; j < 16; ++j)
        asm volatile("" : "+v"(Wr00[j]), "+v"(Wr01[j]), "+v"(Wr10[j]), "+v"(Wr11[j]));

    // U2[f] = (U[2p][f], U[2p+1][f]) — used once per step (outside the iter
    // loop); remat of these is cheap, leave unpinned.
    f32x2 U2[NF];
#pragma unroll
    for (int f = 0; f < NF; f += 4) {
        f32x4 r0 = *(const f32x4*)(U + (2*p)   * NF + f);
        f32x4 r1 = *(const f32x4*)(U + (2*p+1) * NF + f);
#pragma unroll
        for (int e = 0; e < 4; ++e) U2[f+e] = (f32x2){r0[e], r1[e]};
    }
    const f32x2 b2 = *(const f32x2*)(bias + 2*p);

    // y_prev, out[0] = y0
    f32x2 yp = *(const f32x2*)(y0 + (size_t)batch * NS + 2*p);
    __builtin_nontemporal_store(yp, (f32x2*)(out + (size_t)batch * NS + 2*p));

    // register prefetch of forces[1]: broadcast f32x4 x4 per b-group.
    const size_t fstep = (size_t)NB * NF;
    const f32x4* fb = (const f32x4*)(forces + (size_t)batch * NF);
    f32x4 upf[4];
#pragma unroll
    for (int j = 0; j < 4; ++j)
        upf[j] = __builtin_nontemporal_load(&fb[(fstep >> 2) + j]);

    for (int k = 1; k < NT; ++k) {
        // fu = U u + b from prefetched registers (2 accumulators)
        f32x2 a0 = b2, a1 = (f32x2){0.f, 0.f};
#pragma unroll
        for (int f = 0; f < NF; f += 4) {
            f32x4 u4 = upf[f >> 2];
            a0 = U2[f+0] * u4[0] + a0;
            a1 = U2[f+1] * u4[1] + a1;
            a0 = U2[f+2] * u4[2] + a0;
            a1 = U2[f+3] * u4[3] + a1;
        }
        const f32x2 fu = a0 + a1;

        // prefetch next step's forces (in flight across all 3 iterations)
        {
            int kn = (k + 1 < NT) ? (k + 1) : (NT - 1);
#pragma unroll
            for (int j = 0; j < 4; ++j)
                upf[j] = __builtin_nontemporal_load(&fb[(size_t)kn * (fstep >> 2) + j]);
        }

        // fixed-point iterations, warm start y_prev. Pure-register: 15
        // INDEPENDENT row_ror:j hops (all read the original y), 4 independent
        // FMA accumulator chains. DPP ctrl literals via macro expansion.
        f32x2 y = yp;
#pragma unroll
        for (int it = 0; it < FP_ITERS; ++it) {
            const int y0i = __float_as_int(y[0]);
            const int y1i = __float_as_int(y[1]);
            float r00 = fu[0], r01 = 0.f, r10 = fu[1], r11 = 0.f;
            // j = 0: own pair, no hop
            r00 = fmaf(Wr00[0], y[0], r00);
            r01 = fmaf(Wr01[0], y[1], r01);
            r10 = fmaf(Wr10[0], y[0], r10);
            r11 = fmaf(Wr11[0], y[1], r11);
#define RNES_HOP(J)                                                            \
            {                                                                  \
                float y0q = __int_as_float(__builtin_amdgcn_update_dpp(        \
                    0, y0i, 0x120 + (J), 0xF, 0xF, true));                     \
                float y1q = __int_as_float(__builtin_amdgcn_update_dpp(        \
                    0, y1i, 0x120 + (J), 0xF, 0xF, true));                     \
                r00 = fmaf(Wr00[J], y0q, r00);                                 \
                r01 = fmaf(Wr01[J], y1q, r01);                                 \
                r10 = fmaf(Wr10[J], y0q, r10);                                 \
                r11 = fmaf(Wr11[J], y1q, r11);                                 \
            }
            RNES_HOP(1)  RNES_HOP(2)  RNES_HOP(3)  RNES_HOP(4)
            RNES_HOP(5)  RNES_HOP(6)  RNES_HOP(7)  RNES_HOP(8)
            RNES_HOP(9)  RNES_HOP(10) RNES_HOP(11) RNES_HOP(12)
            RNES_HOP(13) RNES_HOP(14) RNES_HOP(15)
#undef RNES_HOP
            f32x2 zt;
            zt[0] = r00 + r01;
            zt[1] = r10 + r11;
            f32x2 t = tanh2(zt);
            y[0] = fmaf(DT, t[0], yp[0]);
            y[1] = fmaf(DT, t[1], yp[1]);
        }

        yp = y;
        __builtin_nontemporal_store(y, (f32x2*)(out + ((size_t)k * NB + batch) * NS + 2*p));
    }
}

extern "C" void kernel_launch(void* const* d_in, const int* in_sizes, int n_in,
                              void* d_out, int out_size, void* d_ws, size_t ws_size,
                              hipStream_t stream) {
    const float* y0     = (const float*)d_in[0];
    const float* forces = (const float*)d_in[1];
    const float* W      = (const float*)d_in[2];
    const float* U      = (const float*)d_in[3];
    const float* b      = (const float*)d_in[4];
    float* out = (float*)d_out;

    dim3 grid(NB / 16);   // 512 blocks x 4 waves x 4 batches = 8192
    dim3 block(256);
    rnes_kernel<<<grid, block, 0, stream>>>(y0, forces, W, U, b, out);
}

// Round 6
// 159.779 us; speedup vs baseline: 1.1924x; 1.0715x over previous
//
#include <hip/hip_runtime.h>

#define NT 64
#define NB 8192
#define NS 32
#define NF 16
#define DT 0.05f
#define FP_ITERS 3

typedef float f32x2 __attribute__((ext_vector_type(2)));
typedef float f32x4 __attribute__((ext_vector_type(4)));

// tanh(x) = 1 - 2/(1 + exp2(K x)), K = 2*log2(e). 6 VALU ops per pair.
__device__ __forceinline__ f32x2 tanh2(f32x2 x) {
    const float K = 2.8853900817779268f;
    float e0 = __builtin_amdgcn_exp2f(K * x[0]);
    float e1 = __builtin_amdgcn_exp2f(K * x[1]);
    float r0 = __builtin_amdgcn_rcpf(e0 + 1.0f);
    float r1 = __builtin_amdgcn_rcpf(e1 + 1.0f);
    f32x2 r;
    r[0] = fmaf(-2.0f, r0, 1.0f);
    r[1] = fmaf(-2.0f, r1, 1.0f);
    return r;
}

// Lane map: lane = b*16 + p; b in [0,4) = batch within wave (row_ror rotates
// within 16-lane rows -> exchange is batch-contained), p in [0,16) = state
// pair. 4 batches/wave -> 2048 waves = 2/SIMD.
//
// R5 post-mortem: DS-free DPP loop worked mechanically (LDS=0, VALUBusy 62%)
// but used 64 SCALAR fma/iter vs R1's 32 packed -> VALU-volume-bound at 92us.
// This round restores v_pk_fma_f32 packing ON TOP of the DPP exchange:
//   WA[j] = (W[2p][2q], W[2p][2q+1])   (contiguous f32x2 load, q = hop-j lane)
//   accA  = pk_fma(WA[j], (y0q,y1q), accA)  -> both halves of output row 2p
// One horizontal add per row at the end. Per hop: 2 DPP + 2 pk_fma (was
// 2 DPP + 4 scalar fma). U-side identically packed; ALL loop-invariant
// operands (WA/WB/UA/UB) pinned via asm "+v" against rematerialization.
__global__ __launch_bounds__(256, 2) void rnes_kernel(
    const float* __restrict__ y0,
    const float* __restrict__ forces,
    const float* __restrict__ W,
    const float* __restrict__ U,
    const float* __restrict__ bias,
    float* __restrict__ out)
{
    const int lane = threadIdx.x & 63;
    const int wv   = threadIdx.x >> 6;
    const int b    = lane >> 4;
    const int p    = lane & 15;
    const int batch = blockIdx.x * 16 + wv * 4 + b;

    // One-time DPP direction probe (immune to row_ror receive-direction
    // ambiguity): after ror:1 this lane holds the p of the lane it received
    // from; rotations compose, so ror:j delivers lane (p + dir*j) & 15.
    const int got = __builtin_amdgcn_update_dpp(0, p, 0x121, 0xF, 0xF, true) & 15;
    const int dir = (got == ((p + 1) & 15)) ? 1 : 15;

    // W gathered in rotation order as contiguous column pairs:
    // WA[j] = (W[2p][2q], W[2p][2q+1]), WB[j] = same for row 2p+1. 64 VGPRs.
    f32x2 WA[16], WB[16];
#pragma unroll
    for (int j = 0; j < 16; ++j) {
        const int q = (p + dir * j) & 15;
        WA[j] = *(const f32x2*)(W + (2*p)   * NS + 2*q);
        WB[j] = *(const f32x2*)(W + (2*p+1) * NS + 2*q);
    }
#pragma unroll
    for (int j = 0; j < 16; ++j)
        asm volatile("" : "+v"(WA[j]), "+v"(WB[j]));   // anti-remat pin

    // U as packed feature pairs: UA[f] = (U[2p][2f], U[2p][2f+1]). 32 VGPRs.
    f32x2 UA[8], UB[8];
#pragma unroll
    for (int f = 0; f < 8; ++f) {
        UA[f] = *(const f32x2*)(U + (2*p)   * NF + 2*f);
        UB[f] = *(const f32x2*)(U + (2*p+1) * NF + 2*f);
    }
#pragma unroll
    for (int f = 0; f < 8; ++f)
        asm volatile("" : "+v"(UA[f]), "+v"(UB[f]));   // anti-remat pin

    const f32x2 b2 = *(const f32x2*)(bias + 2*p);

    // y_prev, out[0] = y0
    f32x2 yp = *(const f32x2*)(y0 + (size_t)batch * NS + 2*p);
    __builtin_nontemporal_store(yp, (f32x2*)(out + (size_t)batch * NS + 2*p));

    // register prefetch of forces[1]: broadcast f32x4 x4 per b-group.
    const size_t fstep = (size_t)NB * NF;
    const f32x4* fb = (const f32x4*)(forces + (size_t)batch * NF);
    f32x4 upf[4];
#pragma unroll
    for (int j = 0; j < 4; ++j)
        upf[j] = __builtin_nontemporal_load(&fb[(fstep >> 2) + j]);

    for (int k = 1; k < NT; ++k) {
        // fu = U u + b, packed: sA accumulates both halves of row 2p.
        f32x2 sA = (f32x2){0.f, 0.f}, sB = (f32x2){0.f, 0.f};
#pragma unroll
        for (int f = 0; f < 8; ++f) {
            f32x4 u4 = upf[f >> 1];
            f32x2 u2 = (f & 1) ? (f32x2){u4[2], u4[3]} : (f32x2){u4[0], u4[1]};
            sA = UA[f] * u2 + sA;
            sB = UB[f] * u2 + sB;
        }
        const float fu0 = b2[0] + sA[0] + sA[1];
        const float fu1 = b2[1] + sB[0] + sB[1];

        // prefetch next step's forces (in flight across all 3 iterations)
        {
            int kn = (k + 1 < NT) ? (k + 1) : (NT - 1);
#pragma unroll
            for (int j = 0; j < 4; ++j)
                upf[j] = __builtin_nontemporal_load(&fb[(size_t)kn * (fstep >> 2) + j]);
        }

        // fixed-point iterations, warm start y_prev. Pure-register: 15
        // INDEPENDENT row_ror:j hops (all read the original y pair), packed
        // FMA accumulation, no memory ops.
        f32x2 y = yp;
#pragma unroll
        for (int it = 0; it < FP_ITERS; ++it) {
            const int y0i = __float_as_int(y[0]);
            const int y1i = __float_as_int(y[1]);
            f32x2 accA = (f32x2){fu0, 0.f};
            f32x2 accB = (f32x2){fu1, 0.f};
            // j = 0: own pair, no hop
            accA = WA[0] * y + accA;
            accB = WB[0] * y + accB;
#define RNES_HOP(J)                                                            \
            {                                                                  \
                f32x2 yq;                                                      \
                yq[0] = __int_as_float(__builtin_amdgcn_update_dpp(            \
                    0, y0i, 0x120 + (J), 0xF, 0xF, true));                     \
                yq[1] = __int_as_float(__builtin_amdgcn_update_dpp(            \
                    0, y1i, 0x120 + (J), 0xF, 0xF, true));                     \
                accA = WA[J] * yq + accA;                                      \
                accB = WB[J] * yq + accB;                                      \
            }
            RNES_HOP(1)  RNES_HOP(2)  RNES_HOP(3)  RNES_HOP(4)
            RNES_HOP(5)  RNES_HOP(6)  RNES_HOP(7)  RNES_HOP(8)
            RNES_HOP(9)  RNES_HOP(10) RNES_HOP(11) RNES_HOP(12)
            RNES_HOP(13) RNES_HOP(14) RNES_HOP(15)
#undef RNES_HOP
            f32x2 zt;
            zt[0] = accA[0] + accA[1];
            zt[1] = accB[0] + accB[1];
            f32x2 t = tanh2(zt);
            y[0] = fmaf(DT, t[0], yp[0]);
            y[1] = fmaf(DT, t[1], yp[1]);
        }

        yp = y;
        __builtin_nontemporal_store(y, (f32x2*)(out + ((size_t)k * NB + batch) * NS + 2*p));
    }
}

extern "C" void kernel_launch(void* const* d_in, const int* in_sizes, int n_in,
                              void* d_out, int out_size, void* d_ws, size_t ws_size,
                              hipStream_t stream) {
    const float* y0     = (const float*)d_in[0];
    const float* forces = (const float*)d_in[1];
    const float* W      = (const float*)d_in[2];
    const float* U      = (const float*)d_in[3];
    const float* b      = (const float*)d_in[4];
    float* out = (float*)d_out;

    dim3 grid(NB / 16);   // 512 blocks x 4 waves x 4 batches = 8192
    dim3 block(256);
    rnes_kernel<<<grid, block, 0, stream>>>(y0, forces, W, U, b, out);
}